// Round 4
// baseline (245.563 us; speedup 1.0000x reference)
//
#include <hip/hip_runtime.h>

typedef __attribute__((ext_vector_type(8))) short short8;
typedef __attribute__((ext_vector_type(4))) float f32x4;

constexpr int B_ = 4, T_ = 12, N_ = 2000, K_ = 10, F_ = 64, H_ = 8;
constexpr int AST = 72;   // A-tile stride (bf16): 144B rows -> 16B-aligned, conflict-free b128 reads

// fp32 -> bf16 (RNE) and back, bit ops
static __device__ __forceinline__ short f2bf(float f) {
    unsigned u = __float_as_uint(f);
    return (short)((u + 0x7FFFu + ((u >> 16) & 1u)) >> 16);
}
static __device__ __forceinline__ float bf2f(short s) {
    return __uint_as_float(((unsigned)(unsigned short)s) << 16);
}

__global__ __launch_bounds__(256, 5)
void gconv_mfma(const float* __restrict__ x,
                const float* __restrict__ dist,
                const float* __restrict__ W,
                const float* __restrict__ bias,
                const int*   __restrict__ idx,
                float* __restrict__ out)
{
    __shared__ short Ahi[96 * AST];   // 13.8 KB
    __shared__ short Alo[96 * AST];   // 13.8 KB   (total 27.6 KB -> 5 blocks/CU)

    const int tid  = threadIdx.x;
    const int wave = tid >> 6;
    const int lane = tid & 63;
    const int n = blockIdx.x % N_;
    const int b = blockIdx.x / N_;
    const int t0 = wave * 3;                    // wave owns blended t in [t0, t0+3)

    // ---- W fragments: issue block-invariant loads first (hide under gather) ----
    const int colw = (wave << 4) + (lane & 15); // output col this lane produces
    const int kg   = lane >> 4;                 // k-group for MFMA B-fragment
    float wf[16];
    #pragma unroll
    for (int kb = 0; kb < 2; ++kb) {
        const float* wp = W + colw * F_ + kb * 32 + kg * 8;
        #pragma unroll
        for (int j = 0; j < 8; ++j) wf[kb * 8 + j] = wp[j];
    }
    const float bs = bias[colw];

    // ---- neighbor indices (block-uniform -> scalar) + base weights ----
    float rk[K_]; int nb[K_];
    #pragma unroll
    for (int k = 0; k < K_; ++k) {
        nb[k] = idx[n * K_ + k] * F_;
        float d = dist[n * K_ + k];
        rk[k] = __expf(d * d * (-1.0f / 288.0f));   // w[k][h] = rk^(h+1)
    }

    // ---- gather-FMA: raw agg rows t0-1 .. t0+2, f = lane (wave-local blend) ----
    float rm[H_], r0[H_], r1[H_], r2[H_];
    #pragma unroll
    for (int h = 0; h < H_; ++h) { rm[h] = 0.f; r0[h] = 0.f; r1[h] = 0.f; r2[h] = 0.f; }

    const size_t bstr = (size_t)N_ * F_;
    const float* xb = x + ((size_t)b * T_ + t0) * bstr + lane;
    const float* xm = (wave > 0) ? xb - bstr : xb;   // clamped for wave 0 (value unused)
    #pragma unroll
    for (int k = 0; k < K_; ++k) {
        float xmv = xm[nb[k]];
        float x0  = xb[nb[k]];
        float x1  = xb[nb[k] + bstr];
        float x2  = xb[nb[k] + 2 * bstr];
        float wgt = rk[k];
        #pragma unroll
        for (int h = 0; h < H_; ++h) {
            rm[h] = fmaf(xmv, wgt, rm[h]);
            r0[h] = fmaf(x0,  wgt, r0[h]);
            r1[h] = fmaf(x1,  wgt, r1[h]);
            r2[h] = fmaf(x2,  wgt, r2[h]);
            wgt *= rk[k];
        }
    }

    // ---- blend (in registers, wave-local) + write A hi/lo to LDS ----
    #pragma unroll
    for (int h = 0; h < H_; ++h) {
        float b2 = fmaf(0.8f, r2[h], 0.2f * r1[h]);
        float b1 = fmaf(0.8f, r1[h], 0.2f * r0[h]);
        float b0 = (wave == 0) ? r0[h] : fmaf(0.8f, r0[h], 0.2f * rm[h]);
        float v[3] = {b0, b1, b2};
        #pragma unroll
        for (int i = 0; i < 3; ++i) {
            int m = (t0 + i) * H_ + h;
            short hi = f2bf(v[i]);
            Ahi[m * AST + lane] = hi;
            Alo[m * AST + lane] = f2bf(v[i] - bf2f(hi));
        }
    }

    // ---- convert W fragments (overlaps barrier wait) ----
    short8 bh[2], bl[2];
    #pragma unroll
    for (int kb = 0; kb < 2; ++kb)
        #pragma unroll
        for (int j = 0; j < 8; ++j) {
            float wv = wf[kb * 8 + j];
            short hi = f2bf(wv);
            bh[kb][j] = hi;
            bl[kb][j] = f2bf(wv - bf2f(hi));
        }

    __syncthreads();   // the only barrier: A-tile transpose visibility

    // ---- MFMA GEMM + direct bias/ReLU store per tile ----
    #pragma unroll
    for (int mt = 0; mt < 6; ++mt) {
        const short* ap = &Ahi[(mt * 16 + (lane & 15)) * AST + kg * 8];
        const short* lp = &Alo[(mt * 16 + (lane & 15)) * AST + kg * 8];
        short8 a0 = *(const short8*)ap;
        short8 a1 = *(const short8*)(ap + 32);
        short8 l0 = *(const short8*)lp;
        short8 l1 = *(const short8*)(lp + 32);

        f32x4 c = {0.f, 0.f, 0.f, 0.f};
        c = __builtin_amdgcn_mfma_f32_16x16x32_bf16(a0, bl[0], c, 0, 0, 0);
        c = __builtin_amdgcn_mfma_f32_16x16x32_bf16(a1, bl[1], c, 0, 0, 0);
        c = __builtin_amdgcn_mfma_f32_16x16x32_bf16(l0, bh[0], c, 0, 0, 0);
        c = __builtin_amdgcn_mfma_f32_16x16x32_bf16(l1, bh[1], c, 0, 0, 0);
        c = __builtin_amdgcn_mfma_f32_16x16x32_bf16(a0, bh[0], c, 0, 0, 0);
        c = __builtin_amdgcn_mfma_f32_16x16x32_bf16(a1, bh[1], c, 0, 0, 0);

        // D layout: col = lane&15 (=colw), row = (lane>>4)*4 + r
        #pragma unroll
        for (int r = 0; r < 4; ++r) {
            int m = mt * 16 + (lane >> 4) * 4 + r;
            int t = m >> 3, h = m & 7;
            float v = fmaxf(c[r] + bs, 0.f);
            out[(((size_t)(b * T_ + t) * N_ + n) * H_ + h) * F_ + colw] = v;
        }
    }
}

extern "C" void kernel_launch(void* const* d_in, const int* in_sizes, int n_in,
                              void* d_out, int out_size, void* d_ws, size_t ws_size,
                              hipStream_t stream) {
    const float* x    = (const float*)d_in[0];
    const float* dist = (const float*)d_in[1];
    const float* W    = (const float*)d_in[2];
    const float* bias = (const float*)d_in[3];
    const int*   idx  = (const int*)d_in[4];
    float* out = (float*)d_out;

    hipLaunchKernelGGL(gconv_mfma, dim3(B_ * N_), dim3(256), 0, stream,
                       x, dist, W, bias, idx, out);
}